// Round 7
// baseline (528.757 us; speedup 1.0000x reference)
//
#include <hip/hip_runtime.h>

#define LREL(x) ((x) > 0.0f ? (x) : 0.2f * (x))

// Zero cnt (2N ints) + compute bk[k] = sum_c b1cat[c]*W2[c,k] (bias through layer-2 proj)
__global__ void k_prep(int* __restrict__ cnt, int n, const float* __restrict__ b1,
                       const float* __restrict__ W2, float* __restrict__ bk) {
    int i = blockIdx.x * blockDim.x + threadIdx.x;
    int st = gridDim.x * blockDim.x;
    for (; i < n; i += st) cnt[i] = 0;
    if (blockIdx.x == 0 && threadIdx.x < 2) {
        int k = threadIdx.x;
        float acc = 0.f;
#pragma unroll
        for (int c = 0; c < 256; ++c) acc = fmaf(b1[c & 127], W2[c * 2 + k], acc);
        bk[k] = acc;
    }
}

// Fused layer-1 projection: el1/er1 [N,2] and g [N][rel][h][k] (8 floats/node).
// h1 never touches memory. g[s,rel,h,k] = sum_o h1[s,h*64+o] * W2[(rel*128+h*64+o)*2+k].
// One block (128 thr = 2 waves) per node; wave h owns channels h*64+lane.
__global__ void k_gemm1g(const float* __restrict__ x, const float* __restrict__ W1,
                         const float* __restrict__ aL1, const float* __restrict__ aR1,
                         const float* __restrict__ W2,
                         float* __restrict__ el1, float* __restrict__ er1,
                         float* __restrict__ g, int N) {
    int n = blockIdx.x;
    int j = threadIdx.x;  // 0..127
    int h = j >> 6, lane = j & 63;
    __shared__ float xs[32];
    if (j < 32) xs[j] = x[(long)n * 32 + j];
    __syncthreads();
    float acc = 0.f;
#pragma unroll
    for (int k = 0; k < 32; ++k) acc = fmaf(xs[k], W1[k * 128 + j], acc);
    float vl = acc * aL1[j];
    float vr = acc * aR1[j];
    float2 w2r0 = *(const float2*)(W2 + 2 * j);          // W2 row c=j       (rel 0)
    float2 w2r1 = *(const float2*)(W2 + 2 * (128 + j));  // W2 row c=128+j   (rel 1)
    float g00 = acc * w2r0.x, g01 = acc * w2r0.y;
    float g10 = acc * w2r1.x, g11 = acc * w2r1.y;
#pragma unroll
    for (int off = 32; off; off >>= 1) {
        vl  += __shfl_down(vl, off);
        vr  += __shfl_down(vr, off);
        g00 += __shfl_down(g00, off);
        g01 += __shfl_down(g01, off);
        g10 += __shfl_down(g10, off);
        g11 += __shfl_down(g11, off);
    }
    if (lane == 0) {
        el1[n * 2 + h] = vl;
        er1[n * 2 + h] = vr;
        float* gp = g + (long)n * 8;  // [rel][h][k]
        gp[0 + h * 2 + 0] = g00;
        gp[0 + h * 2 + 1] = g01;
        gp[4 + h * 2 + 0] = g10;
        gp[4 + h * 2 + 1] = g11;
    }
}

// Degree count: fire-and-forget atomics (no dependent use of the return value).
__global__ void k_count(const int* __restrict__ dstF, const int* __restrict__ dstL,
                        int* __restrict__ cnt, int N, int E) {
    int e = blockIdx.x * blockDim.x + threadIdx.x;
    if (e >= E) return;
    atomicAdd(&cnt[dstF[e]], 1);
    atomicAdd(&cnt[N + dstL[e]], 1);
}

// Single-block exclusive scan of cnt[0..n) -> off[0..n] and cur[0..n) (place cursors).
__global__ void k_scan(const int* __restrict__ cnt, int* __restrict__ off,
                       int* __restrict__ cur, int n) {
    const int T = 1024;
    __shared__ int ls[T];
    int tid = threadIdx.x;
    int chunk = (n + T - 1) / T;
    int lo = tid * chunk;
    int hi = lo + chunk; if (hi > n) hi = n; if (lo > n) lo = n;
    int s = 0;
    for (int i = lo; i < hi; ++i) s += cnt[i];
    ls[tid] = s;
    __syncthreads();
    // Hillis-Steele inclusive scan over 1024 partials
    for (int o = 1; o < T; o <<= 1) {
        int v = (tid >= o) ? ls[tid - o] : 0;
        __syncthreads();
        ls[tid] += v;
        __syncthreads();
    }
    int run = ls[tid] - s;  // exclusive prefix of this thread's chunk
    for (int i = lo; i < hi; ++i) {
        off[i] = run;
        cur[i] = run;
        run += cnt[i];
    }
    if (tid == T - 1) off[n] = run;  // = 2E
}

// Place edges into compact CSR. Slot order is atomic-arrival-order (replay-varying)
// but each bucket's SET is exact (capacity == degree, no overflow possible).
// atomicExch (no-return swap) keeps the scattered store memory-side.
__global__ void k_place(const int* __restrict__ srcF, const int* __restrict__ dstF,
                        const int* __restrict__ srcL, const int* __restrict__ dstL,
                        int* __restrict__ cur, int* __restrict__ bkt, int N, int E) {
    int e = blockIdx.x * blockDim.x + threadIdx.x;
    if (e >= E) return;
    {
        int s = srcF[e];
        int p = atomicAdd(&cur[dstF[e]], 1);
        atomicExch(&bkt[p], s);
    }
    {
        int s = srcL[e];
        int p = atomicAdd(&cur[N + dstL[e]], 1);
        atomicExch(&bkt[p], s);
    }
}

// Layer-1 softmax-aggregation in g-space, fused with the cross-(rel,h) combine into h2.
// Thread t = d*2+rel; bucket index b = rel*N+d. Pair (2d,2d+1) exchanges via LDS.
__global__ void k_agg1(const int* __restrict__ off, const int* __restrict__ bkt,
                       const float* __restrict__ el1, const float* __restrict__ er1,
                       const float* __restrict__ g, const float* __restrict__ bk,
                       float* __restrict__ h2, int N) {
    __shared__ float4 sh[256];
    int t = blockIdx.x * blockDim.x + threadIdx.x;
    int d = t >> 1, rel = t & 1;
    float4 r = make_float4(0.f, 0.f, 0.f, 0.f);
    if (d < N) {
        int b = rel * N + d;
        int j0 = off[b], j1 = off[b + 1];
        float2 erd = *(const float2*)(er1 + 2 * d);
        float n00 = 0.f, n01 = 0.f, n10 = 0.f, n11 = 0.f, ws0 = 0.f, ws1 = 0.f;
        for (int j = j0; j < j1; ++j) {
            int s = bkt[j];
            float2 els = *(const float2*)(el1 + 2 * s);
            float4 gv = *(const float4*)(g + (long)s * 8 + rel * 4);  // {h0k0,h0k1,h1k0,h1k1}
            float w0 = __expf(LREL(els.x + erd.x));
            float w1 = __expf(LREL(els.y + erd.y));
            n00 = fmaf(w0, gv.x, n00);
            n01 = fmaf(w0, gv.y, n01);
            n10 = fmaf(w1, gv.z, n10);
            n11 = fmaf(w1, gv.w, n11);
            ws0 += w0;
            ws1 += w1;
        }
        if (j1 > j0) {
            r.x = n00 / ws0; r.y = n01 / ws0;
            r.z = n10 / ws1; r.w = n11 / ws1;
        }
    }
    sh[threadIdx.x] = r;
    __syncthreads();
    if (d < N && rel == 0) {
        float4 q = sh[threadIdx.x + 1];  // partner: same d, rel=1
        float2 o;
        o.x = bk[0] + r.x + r.z + q.x + q.z;  // k=0: sum over (rel,h)
        o.y = bk[1] + r.y + r.w + q.y + q.w;  // k=1
        *(float2*)(h2 + 2 * d) = o;
    }
}

// Layer-2 softmax-aggregation + output. Thread t = d*2+rel; bucket b = rel*N+d. O=1.
__global__ void k_agg2(const int* __restrict__ off, const int* __restrict__ bkt,
                       const float* __restrict__ h2, const float* __restrict__ aL2,
                       const float* __restrict__ aR2, const float* __restrict__ b2,
                       float* __restrict__ out, int N) {
    int t = blockIdx.x * blockDim.x + threadIdx.x;
    if (t >= N * 2) return;
    int d = t >> 1, rel = t & 1;
    int b = rel * N + d;
    int j0 = off[b], j1 = off[b + 1];
    float aL0 = aL2[0], aL1_ = aL2[1];
    float2 h2d = *(const float2*)(h2 + 2 * d);
    float er0 = h2d.x * aR2[0], er1_ = h2d.y * aR2[1];
    float n0 = 0.f, n1 = 0.f, w0s = 0.f, w1s = 0.f;
    for (int j = j0; j < j1; ++j) {
        int s = bkt[j];
        float2 h2s = *(const float2*)(h2 + 2 * s);
        float w0 = __expf(LREL(h2s.x * aL0 + er0));
        float w1 = __expf(LREL(h2s.y * aL1_ + er1_));
        n0 = fmaf(w0, h2s.x, n0);
        n1 = fmaf(w1, h2s.y, n1);
        w0s += w0;
        w1s += w1;
    }
    int deg = j1 - j0;
    out[d * 4 + rel * 2 + 0] = (deg ? n0 / w0s : 0.f) + b2[0];
    out[d * 4 + rel * 2 + 1] = (deg ? n1 / w1s : 0.f) + b2[1];
}

extern "C" void kernel_launch(void* const* d_in, const int* in_sizes, int n_in,
                              void* d_out, int out_size, void* d_ws, size_t ws_size,
                              hipStream_t stream) {
    const float* x   = (const float*)d_in[0];
    const float* W1  = (const float*)d_in[1];
    const float* aL1 = (const float*)d_in[2];
    const float* aR1 = (const float*)d_in[3];
    const float* b1  = (const float*)d_in[4];
    const float* W2  = (const float*)d_in[5];
    const float* aL2 = (const float*)d_in[6];
    const float* aR2 = (const float*)d_in[7];
    const float* b2  = (const float*)d_in[8];
    const int* srcF  = (const int*)d_in[9];
    const int* dstF  = (const int*)d_in[10];
    const int* srcL  = (const int*)d_in[11];
    const int* dstL  = (const int*)d_in[12];
    float* out = (float*)d_out;

    const int N = in_sizes[0] / 32;
    const int E = in_sizes[9];

    // Workspace: el1 2N | er1 2N | g 8N | h2 2N | bk 16 || cnt 2N | off 2N+1 | cur 2N | bkt 2E
    float* ws  = (float*)d_ws;
    float* el1 = ws;                      // 2N
    float* er1 = el1 + (long)2 * N;       // 2N
    float* g   = er1 + (long)2 * N;       // 8N  (byte offset 16N — 16B-aligned)
    float* h2  = g + (long)8 * N;         // 2N
    float* bk  = h2 + (long)2 * N;        // 16
    int* cnt   = (int*)(bk + 16);         // 2N
    int* off   = cnt + (long)2 * N;       // 2N+1
    int* cur   = off + (long)2 * N + 1;   // 2N
    int* bkt   = cur + (long)2 * N;       // 2E (compact: capacity == total degree)
    // total ~= 14N*4 + (6N+1)*4 + 2E*4 bytes ~= 10.4 MB

    k_prep<<<128, 256, 0, stream>>>(cnt, 2 * N, b1, W2, bk);
    k_gemm1g<<<N, 128, 0, stream>>>(x, W1, aL1, aR1, W2, el1, er1, g, N);

    int eb = (E + 255) / 256;
    k_count<<<eb, 256, 0, stream>>>(dstF, dstL, cnt, N, E);
    k_scan<<<1, 1024, 0, stream>>>(cnt, off, cur, 2 * N);
    k_place<<<eb, 256, 0, stream>>>(srcF, dstF, srcL, dstL, cur, bkt, N, E);

    int nb = (N * 2 + 255) / 256;
    k_agg1<<<nb, 256, 0, stream>>>(off, bkt, el1, er1, g, bk, h2, N);
    k_agg2<<<nb, 256, 0, stream>>>(off, bkt, h2, aL2, aR2, b2, out, N);
}

// Round 8
// 262.584 us; speedup vs baseline: 2.0137x; 2.0137x over previous
//
#include <hip/hip_runtime.h>

#define LREL(x) ((x) > 0.0f ? (x) : 0.2f * (x))

// head = -1 fill (2N ints) + bk[k] = sum_c b1cat[c]*W2[c,k] (layer-1 bias through layer-2 proj)
__global__ void k_prep(int* __restrict__ head, int n, const float* __restrict__ b1,
                       const float* __restrict__ W2, float* __restrict__ bk) {
    int i = blockIdx.x * blockDim.x + threadIdx.x;
    int st = gridDim.x * blockDim.x;
    for (; i < n; i += st) head[i] = -1;
    if (blockIdx.x == 0 && threadIdx.x < 2) {
        int k = threadIdx.x;
        float acc = 0.f;
#pragma unroll
        for (int c = 0; c < 256; ++c) acc = fmaf(b1[c & 127], W2[c * 2 + k], acc);
        bk[k] = acc;
    }
}

// Fused layer-1 projection: el1/er1 [N,2] and g [N][rel][h][k] (8 floats/node).
// h1 never touches memory. g[s,rel,h,k] = sum_o h1[s,h*64+o] * W2[(rel*128+h*64+o)*2+k].
// One block (128 thr = 2 waves) per node; wave h owns channels h*64+lane.
__global__ void k_gemm1g(const float* __restrict__ x, const float* __restrict__ W1,
                         const float* __restrict__ aL1, const float* __restrict__ aR1,
                         const float* __restrict__ W2,
                         float* __restrict__ el1, float* __restrict__ er1,
                         float* __restrict__ g, int N) {
    int n = blockIdx.x;
    int j = threadIdx.x;  // 0..127
    int h = j >> 6, lane = j & 63;
    __shared__ float xs[32];
    if (j < 32) xs[j] = x[(long)n * 32 + j];
    __syncthreads();
    float acc = 0.f;
#pragma unroll
    for (int k = 0; k < 32; ++k) acc = fmaf(xs[k], W1[k * 128 + j], acc);
    float vl = acc * aL1[j];
    float vr = acc * aR1[j];
    float2 w2r0 = *(const float2*)(W2 + 2 * j);          // W2 row c=j       (rel 0)
    float2 w2r1 = *(const float2*)(W2 + 2 * (128 + j));  // W2 row c=128+j   (rel 1)
    float g00 = acc * w2r0.x, g01 = acc * w2r0.y;
    float g10 = acc * w2r1.x, g11 = acc * w2r1.y;
#pragma unroll
    for (int off = 32; off; off >>= 1) {
        vl  += __shfl_down(vl, off);
        vr  += __shfl_down(vr, off);
        g00 += __shfl_down(g00, off);
        g01 += __shfl_down(g01, off);
        g10 += __shfl_down(g10, off);
        g11 += __shfl_down(g11, off);
    }
    if (lane == 0) {
        el1[n * 2 + h] = vl;
        er1[n * 2 + h] = vr;
        float* gp = g + (long)n * 8;  // [rel][h][k]
        gp[0 + h * 2 + 0] = g00;
        gp[0 + h * 2 + 1] = g01;
        gp[4 + h * 2 + 0] = g10;
        gp[4 + h * 2 + 1] = g11;
    }
}

// Linked-list adjacency build. head[d] / head[N+d] = most-recent edge id (rel1 ids are E+e);
// next[] written CONTIGUOUSLY by edge id (streaming full-line stores). Only the 400 KB head
// array takes scattered atomics. Chain order is replay-varying; the SET per dst is exact.
__global__ void k_build(const int* __restrict__ dstF, const int* __restrict__ dstL,
                        int* __restrict__ head, int* __restrict__ next, int N, int E) {
    int e = blockIdx.x * blockDim.x + threadIdx.x;
    if (e >= E) return;
    int o0 = atomicExch(&head[dstF[e]], e);
    next[e] = o0;
    int o1 = atomicExch(&head[N + dstL[e]], E + e);
    next[E + e] = o1;
}

// Layer-1 softmax-aggregation in g-space + cross-(rel,h) combine into h2.
// One thread per dst node d; chases BOTH relation chains interleaved (2x MLP).
__global__ void k_agg1(const int* __restrict__ head, const int* __restrict__ next,
                       const int* __restrict__ srcF, const int* __restrict__ srcL,
                       const float* __restrict__ el1, const float* __restrict__ er1,
                       const float* __restrict__ g, const float* __restrict__ bk,
                       float* __restrict__ h2, int N, int E) {
    int d = blockIdx.x * blockDim.x + threadIdx.x;
    if (d >= N) return;
    float2 erd = *(const float2*)(er1 + 2 * d);
    float a00 = 0.f, a01 = 0.f, a10 = 0.f, a11 = 0.f, w0s = 0.f, w1s = 0.f;  // rel 0
    float b00 = 0.f, b01 = 0.f, b10 = 0.f, b11 = 0.f, v0s = 0.f, v1s = 0.f;  // rel 1
    int i0 = head[d], i1 = head[N + d];
    bool has0 = i0 >= 0, has1 = i1 >= 0;
    while (i0 >= 0 || i1 >= 0) {
        if (i0 >= 0) {
            int n0 = next[i0];
            int s = srcF[i0];
            float2 els = *(const float2*)(el1 + 2 * s);
            float4 gv = *(const float4*)(g + (long)s * 8);      // rel 0: {h0k0,h0k1,h1k0,h1k1}
            float w0 = __expf(LREL(els.x + erd.x));
            float w1 = __expf(LREL(els.y + erd.y));
            a00 = fmaf(w0, gv.x, a00);
            a01 = fmaf(w0, gv.y, a01);
            a10 = fmaf(w1, gv.z, a10);
            a11 = fmaf(w1, gv.w, a11);
            w0s += w0;
            w1s += w1;
            i0 = n0;
        }
        if (i1 >= 0) {
            int n1 = next[i1];
            int s = srcL[i1 - E];
            float2 els = *(const float2*)(el1 + 2 * s);
            float4 gv = *(const float4*)(g + (long)s * 8 + 4);  // rel 1
            float w0 = __expf(LREL(els.x + erd.x));
            float w1 = __expf(LREL(els.y + erd.y));
            b00 = fmaf(w0, gv.x, b00);
            b01 = fmaf(w0, gv.y, b01);
            b10 = fmaf(w1, gv.z, b10);
            b11 = fmaf(w1, gv.w, b11);
            v0s += w0;
            v1s += w1;
            i1 = n1;
        }
    }
    float r0 = bk[0], r1 = bk[1];
    if (has0) { r0 += a00 / w0s + a10 / w1s; r1 += a01 / w0s + a11 / w1s; }
    if (has1) { r0 += b00 / v0s + b10 / v1s; r1 += b01 / v0s + b11 / v1s; }
    *(float2*)(h2 + 2 * d) = make_float2(r0, r1);
}

// Layer-2 softmax-aggregation + output. One thread per dst; dual-chain chase; float4 out store.
__global__ void k_agg2(const int* __restrict__ head, const int* __restrict__ next,
                       const int* __restrict__ srcF, const int* __restrict__ srcL,
                       const float* __restrict__ h2, const float* __restrict__ aL2,
                       const float* __restrict__ aR2, const float* __restrict__ b2,
                       float* __restrict__ out, int N, int E) {
    int d = blockIdx.x * blockDim.x + threadIdx.x;
    if (d >= N) return;
    float aL0 = aL2[0], aL1_ = aL2[1];
    float2 hd = *(const float2*)(h2 + 2 * d);
    float er0 = hd.x * aR2[0], er1_ = hd.y * aR2[1];
    float n0 = 0.f, n1 = 0.f, s0 = 0.f, s1 = 0.f;  // rel 0: numer h0,h1; denom h0,h1
    float m0 = 0.f, m1 = 0.f, t0 = 0.f, t1 = 0.f;  // rel 1
    int i0 = head[d], i1 = head[N + d];
    bool has0 = i0 >= 0, has1 = i1 >= 0;
    while (i0 >= 0 || i1 >= 0) {
        if (i0 >= 0) {
            int nx = next[i0];
            int s = srcF[i0];
            float2 hs = *(const float2*)(h2 + 2 * s);
            float w0 = __expf(LREL(hs.x * aL0 + er0));
            float w1 = __expf(LREL(hs.y * aL1_ + er1_));
            n0 = fmaf(w0, hs.x, n0);
            n1 = fmaf(w1, hs.y, n1);
            s0 += w0;
            s1 += w1;
            i0 = nx;
        }
        if (i1 >= 0) {
            int nx = next[i1];
            int s = srcL[i1 - E];
            float2 hs = *(const float2*)(h2 + 2 * s);
            float w0 = __expf(LREL(hs.x * aL0 + er0));
            float w1 = __expf(LREL(hs.y * aL1_ + er1_));
            m0 = fmaf(w0, hs.x, m0);
            m1 = fmaf(w1, hs.y, m1);
            t0 += w0;
            t1 += w1;
            i1 = nx;
        }
    }
    float4 o;
    o.x = (has0 ? n0 / s0 : 0.f) + b2[0];
    o.y = (has0 ? n1 / s1 : 0.f) + b2[1];
    o.z = (has1 ? m0 / t0 : 0.f) + b2[0];
    o.w = (has1 ? m1 / t1 : 0.f) + b2[1];
    *(float4*)(out + (long)d * 4) = o;
}

extern "C" void kernel_launch(void* const* d_in, const int* in_sizes, int n_in,
                              void* d_out, int out_size, void* d_ws, size_t ws_size,
                              hipStream_t stream) {
    const float* x   = (const float*)d_in[0];
    const float* W1  = (const float*)d_in[1];
    const float* aL1 = (const float*)d_in[2];
    const float* aR1 = (const float*)d_in[3];
    const float* b1  = (const float*)d_in[4];
    const float* W2  = (const float*)d_in[5];
    const float* aL2 = (const float*)d_in[6];
    const float* aR2 = (const float*)d_in[7];
    const float* b2  = (const float*)d_in[8];
    const int* srcF  = (const int*)d_in[9];
    const int* dstF  = (const int*)d_in[10];
    const int* srcL  = (const int*)d_in[11];
    const int* dstL  = (const int*)d_in[12];
    float* out = (float*)d_out;

    const int N = in_sizes[0] / 32;
    const int E = in_sizes[9];

    // Workspace: el1 2N | er1 2N | g 8N | h2 2N | bk 16 || head 2N (int) | next 2E (int)
    float* ws  = (float*)d_ws;
    float* el1 = ws;                     // 2N
    float* er1 = el1 + (long)2 * N;      // 2N
    float* g   = er1 + (long)2 * N;      // 8N  (byte offset 16N — 16B-aligned)
    float* h2  = g + (long)8 * N;        // 2N
    float* bk  = h2 + (long)2 * N;       // 16
    int* head  = (int*)(bk + 16);        // 2N
    int* next  = head + (long)2 * N;     // 2E
    // total ~= (14N+16)*4 + (2N+2E)*4 ~= 16.4 MB

    k_prep<<<128, 256, 0, stream>>>(head, 2 * N, b1, W2, bk);
    k_gemm1g<<<N, 128, 0, stream>>>(x, W1, aL1, aR1, W2, el1, er1, g, N);
    k_build<<<(E + 255) / 256, 256, 0, stream>>>(dstF, dstL, head, next, N, E);

    int nb = (N + 255) / 256;
    k_agg1<<<nb, 256, 0, stream>>>(head, next, srcF, srcL, el1, er1, g, bk, h2, N, E);
    k_agg2<<<nb, 256, 0, stream>>>(head, next, srcF, srcL, h2, aL2, aR2, b2, out, N, E);
}